// Round 5
// baseline (41.326 us; speedup 1.0000x reference)
//
#include <hip/hip_runtime.h>
#include <hip/hip_bf16.h>

// CosSim2D (K=3, same-pad, C=32 -> F=32) on MI355X.
// im2col-on-the-fly bf16 MFMA GEMM (M=pixels, K=288, N=32).
// Round 5: persistent blocks + cross-tile software pipeline (T14-style).
//   Rounds 2-4 invariant: ~6% MFMA, ~25% VALU, ~25% HBM, 27% occ -> exposed
//   latency on each block's serial stage->barrier->compute chain. Fix with
//   ILP: while computing tile t from LDS buf, the next tile's 11 float4
//   loads are already in flight into registers (double-buffered LDS).

#define H_ 224
#define W_ 224
#define C_ 32
#define F_ 32

#define NSTEP 18   // K = 288 = 18 * 16
#define HROWS 10   // staged halo rows (8 + 2)
#define HCOLS 34   // staged halo cols (32 + 2)
#define NSLOT 11   // ceil(10*34*8 / 256) float4 load slots per thread
#define SLOTS (HROWS * HCOLS * 8)   // 2720
#define GRIDSZ 512
#define NTILES 1568  // 8 images * 28 row-tiles * 7 col-tiles

typedef __bf16 bf16_t;
typedef bf16_t bf16x8 __attribute__((ext_vector_type(8)));
typedef float f32x16 __attribute__((ext_vector_type(16)));

#define WFRAG_BYTES (NSTEP * 64 * 8 * 2)  // 18432 B

// ---------------- prep (6 blocks): w-norm + exponents + B-fragments ---------
__global__ __launch_bounds__(256) void cos2d_prep(
    const float* __restrict__ w, const float* __restrict__ p,
    const float* __restrict__ q, bf16_t* __restrict__ wfrag,
    float* __restrict__ winv, float* __restrict__ ef) {
  const int tid = threadIdx.x;
  if (blockIdx.x == 0) {
    __shared__ float part[8][32];
    const int f = tid & 31, kg = tid >> 5;
    float s = 0.f;
#pragma unroll
    for (int i = 0; i < 36; ++i) {
      const float v = w[(kg + 8 * i) * F_ + f];
      s += v * v;
    }
    part[kg][f] = s;
    __syncthreads();
    if (tid < 32) {
      float t = 0.f;
#pragma unroll
      for (int g = 0; g < 8; ++g) t += part[g][tid];
      const float qt = q[0] * q[0] * 0.1f;
      winv[tid] = 1.f / (sqrtf(fmaxf(t, 1e-12f)) + qt);
      ef[tid] = p[tid] * p[tid] * 0.01f;
    }
  } else {
    // B-fragment layout for mfma_f32_32x32x16_bf16:
    //   lane l holds col f = l&31, k = s2*16 + (l>>5)*8 + e  (e = 0..7).
    const int t = (blockIdx.x - 1) * 256 + tid;
    if (t < NSTEP * 64) {
      const int s2 = t >> 6, l = t & 63;
      const int ff = l & 31;
      union { bf16_t v[8]; uint4 u; } tv;
#pragma unroll
      for (int e = 0; e < 8; ++e) {
        const int kk = s2 * 16 + ((l >> 5) << 3) + e;
        tv.v[e] = (bf16_t)w[kk * F_ + ff];
      }
      *(uint4*)(wfrag + (size_t)t * 8) = tv.u;
    }
  }
}

// ---------------- main ------------------------------------------------------
__global__ __launch_bounds__(256, 2) void cos2d_main(
    const float* __restrict__ img, const bf16_t* __restrict__ wfrag,
    const float* __restrict__ winv, const float* __restrict__ ef,
    const float* __restrict__ q, float* __restrict__ out) {
  // pixel stride 40 bf16 = 80 B (16B-aligned): 0 read conflicts measured r2/r3.
  __shared__ bf16_t xt[2][HROWS][HCOLS][40];
  __shared__ float ssum[2][HROWS][HCOLS];

  const int tid = threadIdx.x;
  const int lane = tid & 63;
  const int wv = tid >> 6;
  const int lp = lane & 31;

  const float qt = q[0] * q[0] * 0.1f;
  const float efv = ef[lp];     // per-filter exponent (filter = lp)
  const float wnv = winv[lp];   // per-filter 1/(||w||+qt)

  float4 sv[NSLOT];             // next tile's staged pixels (in flight)

  // issue: fire NSLOT independent coalesced float4 loads for `tile`
  auto issue = [&](int tile) {
    const int tw = tile % 7, th = (tile / 7) % 28, b = tile / 196;
    const int h0 = th * 8, w0 = tw * 32;
#pragma unroll
    for (int k = 0; k < NSLOT; ++k) {
      const int idx = tid + k * 256;
      const int pp = idx >> 3, sub = idx & 7;
      const int rr = pp / HCOLS, cc = pp - rr * HCOLS;
      const int hh = h0 - 1 + rr, wc = w0 - 1 + cc;
      float4 v = make_float4(0.f, 0.f, 0.f, 0.f);
      if (idx < SLOTS && (unsigned)hh < H_ && (unsigned)wc < W_)
        v = *(const float4*)(img + ((size_t)(b * H_ + hh) * W_ + wc) * C_ + sub * 4);
      sv[k] = v;
    }
  };

  // commit: registers -> LDS buf (bf16 pack + per-pixel sumsq via 8-lane shfl)
  auto commit = [&](int buf) {
#pragma unroll
    for (int k = 0; k < NSLOT; ++k) {
      const int idx = tid + k * 256;
      if (idx < SLOTS) {   // k<10 always true; k=10 uniform per 8-lane group
        const int pp = idx >> 3, sub = idx & 7;
        const int rr = pp / HCOLS, cc = pp - rr * HCOLS;
        const float4 v = sv[k];
        float s = v.x * v.x + v.y * v.y + v.z * v.z + v.w * v.w;
        s += __shfl_xor(s, 1);
        s += __shfl_xor(s, 2);
        s += __shfl_xor(s, 4);
        union { bf16_t h[4]; uint2 u; } pk;
        pk.h[0] = (bf16_t)v.x; pk.h[1] = (bf16_t)v.y;
        pk.h[2] = (bf16_t)v.z; pk.h[3] = (bf16_t)v.w;
        *(uint2*)&xt[buf][rr][cc][sub * 4] = pk.u;
        if (sub == 0) ssum[buf][rr][cc] = s;
      }
    }
  };

  auto compute = [&](int tile, int buf) {
    const int tw = tile % 7, th = (tile / 7) % 28, b = tile / 196;
    const int h0 = th * 8, w0 = tw * 32;
    const int mr0 = wv * 2;  // this wave's 2 output rows (tile-relative)

    float xinv[2];
#pragma unroll
    for (int t = 0; t < 2; ++t) {
      const int mr = mr0 + t;
      const float xn2 =
          ssum[buf][mr + 0][lp] + ssum[buf][mr + 0][lp + 1] + ssum[buf][mr + 0][lp + 2] +
          ssum[buf][mr + 1][lp] + ssum[buf][mr + 1][lp + 1] + ssum[buf][mr + 1][lp + 2] +
          ssum[buf][mr + 2][lp] + ssum[buf][mr + 2][lp + 1] + ssum[buf][mr + 2][lp + 2];
      xinv[t] = 1.f / (sqrtf(fmaxf(xn2, 1e-12f)) + qt);
    }

    f32x16 acc0, acc1;
#pragma unroll
    for (int i = 0; i < 16; ++i) { acc0[i] = 0.f; acc1[i] = 0.f; }

    // K loop: A lane l -> pixel col = l&31, k = (l>>5)*8+e (8 contig channels
    // from LDS); B streamed from wfrag (L1-resident 18 KB).
    const bf16x8* wf4 = (const bf16x8*)wfrag;
#pragma unroll
    for (int s2 = 0; s2 < NSTEP; ++s2) {
      const bf16x8 bf = wf4[s2 * 64 + lane];
      const int pos = s2 >> 1;
      const int dy = pos / 3, dx = pos - dy * 3;
      const int chof = (s2 & 1) * 16 + ((lane >> 5) << 3);
      const bf16x8 a0 = *(const bf16x8*)&xt[buf][mr0 + 0 + dy][lp + dx][chof];
      const bf16x8 a1 = *(const bf16x8*)&xt[buf][mr0 + 1 + dy][lp + dx][chof];
      acc0 = __builtin_amdgcn_mfma_f32_32x32x16_bf16(a0, bf, acc0, 0, 0, 0);
      acc1 = __builtin_amdgcn_mfma_f32_32x32x16_bf16(a1, bf, acc1, 0, 0, 0);
    }

    // epilogue: C/D col = lane&31 (filter), row = (j&3)+8*(j>>2)+4*(lane>>5)
#pragma unroll
    for (int t = 0; t < 2; ++t) {
      const f32x16& acc = t ? acc1 : acc0;
      const int obase = (b * H_ + h0 + mr0 + t) * W_ + w0;
#pragma unroll
      for (int jj = 0; jj < 16; ++jj) {
        const int row = (jj & 3) + 8 * (jj >> 2) + 4 * (lane >> 5);
        const float xi = __shfl(xinv[t], row);  // xinv of pixel-col `row`
        const float sim = acc[jj] * xi * wnv;
        const float ps = fabsf(sim) + 1e-12f;
        float r = exp2f(efv * __log2f(ps));
        r = copysignf(r, sim);
        out[(size_t)(obase + row) * F_ + lp] = r;
      }
    }
  };

  // ---- software pipeline over this block's tiles (tile, tile+GRIDSZ, ...)
  int tile = blockIdx.x;
  issue(tile);
  commit(0);
  __syncthreads();
  int cur = 0;
  for (;;) {
    const int next = tile + GRIDSZ;
    const bool have_next = next < NTILES;
    if (have_next) issue(next);     // loads fly under compute below
    compute(tile, cur);
    if (!have_next) break;
    __syncthreads();                // readers of xt[cur^1] (2 iters ago) done
    commit(cur ^ 1);
    __syncthreads();                // xt[cur^1] ready
    cur ^= 1;
    tile = next;
  }
}

// ---------------- launch ----------------------------------------------------
extern "C" void kernel_launch(void* const* d_in, const int* in_sizes, int n_in,
                              void* d_out, int out_size, void* d_ws, size_t ws_size,
                              hipStream_t stream) {
  const float* img = (const float*)d_in[0];
  const float* w   = (const float*)d_in[1];
  const float* p   = (const float*)d_in[2];
  const float* q   = (const float*)d_in[3];

  bf16_t* wfrag = (bf16_t*)d_ws;
  float*  winv  = (float*)((char*)d_ws + WFRAG_BYTES);
  float*  ef    = winv + 64;

  cos2d_prep<<<6, 256, 0, stream>>>(w, p, q, wfrag, winv, ef);
  cos2d_main<<<GRIDSZ, 256, 0, stream>>>(img, wfrag, winv, ef, q, (float*)d_out);
}